// Round 1
// baseline (6803.382 us; speedup 1.0000x reference)
//
#include <hip/hip_runtime.h>
#include <cstdint>
#include <cstddef>

// Problem constants
#define Tn 1024
#define Bn 512
#define Hn 256

// Partition: 256 blocks = 16 row-tiles (32 rows) x 16 unit-slices (16 units)
// Wave specialization: waves 0-3 = layer-1 engine, waves 4-7 = layer-2 + head engine.
// LDS strides (fp16 elements) — layout IDENTICAL to the verified 3-phase kernel.
#define H1S 264
#define H2S 264
#define W1S 280   // cols 0..9 x-w, 10..15 zero, 16..271 hh-w, pad
#define W2S 520   // cols 0..255 w_ih1, 256..511 w_hh1, pad
#define WHS 264
#define GWS 20    // per-wave gate scratch row stride (floats)

#define H1_OFF  0
#define H2_OFF  (H1_OFF + 32*H1S*2)      // 16896
#define XB_OFF  (H2_OFF + 32*H2S*2)      // 33792
#define W1_OFF  (XB_OFF + 2*32*16*2)     // 35840
#define W2_OFF  (W1_OFF + 64*W1S*2)      // 71680
#define WH_OFF  (W2_OFF + 64*W2S*2)      // 138240
#define GW_OFF  (WH_OFF + 16*WHS*2)      // 146688
#define B1_OFF  (GW_OFF + 8*16*GWS*4)    // 156928
#define B2_OFF  (B1_OFF + 64*4)
#define BH_OFF  (B2_OFF + 64*4)
#define W2H_OFF (BH_OFF + 16*4)
#define LDS_TOTAL (W2H_OFF + 16*4)       // 157568 B < 160 KiB -> 1 block/CU

// ws layout (bytes)
#define SCORES_OFF 0                      // [1024][512] f32 = 2MB
#define H1G_OFF  (2*1024*1024)            // 4 slots x [512][256] fp16 = 1MB
#define H2G_OFF  (3*1024*1024)            // 1MB
#define FLAG_OFF (4*1024*1024)            // tags1[16][16][4], tags2 at +1024 ints
#define WS_USED  (4*1024*1024 + 8192)

typedef _Float16 v4h __attribute__((ext_vector_type(4)));
typedef float    v4f __attribute__((ext_vector_type(4)));
typedef unsigned long long u64;

__device__ inline float sigm(float x){ return 1.0f/(1.0f + __expf(-x)); }
__device__ inline float tanh_f(float x){ return 1.0f - 2.0f/(1.0f + __expf(2.0f*x)); }

// 64 per-producer-wave tags per row-tile group: lane i watches tag i.
__device__ inline void poll64(const int* tags, int tgt){
    int idx = threadIdx.x & 63;
    while (true){
        int t = __hip_atomic_load(&tags[idx], __ATOMIC_RELAXED, __HIP_MEMORY_SCOPE_AGENT);
        if (__ballot(t < tgt) == 0ull) break;
        __builtin_amdgcn_s_sleep(1);
    }
}

// LSTM elementwise + publish for one 16x16 gate tile (tile-local col = 4*unit+gate).
// Sequential reuse of the wave-private gw scratch is made safe by the lgkmcnt(0)
// fences (DS ops of a wave are processed in order; the second fence guarantees the
// read completed before the next call's writes overwrite the region).
__device__ __forceinline__ void lstm_ew_publish(v4f acc, float* gw, const float* bs,
                                                int n, float& c, _Float16* dst,
                                                int ln15, int ln4)
{
    #pragma unroll
    for (int r = 0; r < 4; ++r) gw[(ln4*4 + r)*GWS + ln15] = acc[r];
    asm volatile("s_waitcnt lgkmcnt(0)" ::: "memory");
    v4f g4 = *(const v4f*)(gw + ln15*GWS + ln4*4);
    asm volatile("s_waitcnt lgkmcnt(0)" ::: "memory");
    v4f bb = *(const v4f*)(bs + n*16 + ln4*4);
    float gi = sigm(g4.x + bb.x), gf = sigm(g4.y + bb.y);
    float gg = tanh_f(g4.z + bb.z), go = sigm(g4.w + bb.w);
    c = gf*c + gi*gg;
    float hn = go * tanh_f(c);
    union { _Float16 h; unsigned short u; } cvt; cvt.h = (_Float16)hn;
    unsigned v32 = cvt.u;
    unsigned p16 = (unsigned)__shfl_xor((int)v32, 16, 64);
    unsigned lo32 = v32 | (p16 << 16);
    unsigned hi32 = (unsigned)__shfl_xor((int)lo32, 32, 64);
    if (ln4 == 0){
        u64 pk = (u64)lo32 | ((u64)hi32 << 32);
        __hip_atomic_store((u64*)dst, pk, __ATOMIC_RELAXED, __HIP_MEMORY_SCOPE_AGENT);
    }
}

__global__ __launch_bounds__(512)
void lstm_pipe(const float* __restrict__ x,
               const float* __restrict__ w_ih0, const float* __restrict__ w_hh0,
               const float* __restrict__ b_ih0, const float* __restrict__ b_hh0,
               const float* __restrict__ w_ih1, const float* __restrict__ w_hh1,
               const float* __restrict__ b_ih1, const float* __restrict__ b_hh1,
               const float* __restrict__ adv_w1, const float* __restrict__ adv_b1,
               const float* __restrict__ adv_w2,
               float* __restrict__ scores, _Float16* __restrict__ h1g,
               _Float16* __restrict__ h2g, int* __restrict__ flags)
{
    extern __shared__ char smem[];
    _Float16* H1l = (_Float16*)(smem + H1_OFF);
    _Float16* H2l = (_Float16*)(smem + H2_OFF);
    _Float16* XBp = (_Float16*)(smem + XB_OFF);
    _Float16* W1l = (_Float16*)(smem + W1_OFF);
    _Float16* W2l = (_Float16*)(smem + W2_OFF);
    _Float16* WHl = (_Float16*)(smem + WH_OFF);
    float* gatesc = (float*)(smem + GW_OFF);
    float* b1s    = (float*)(smem + B1_OFF);
    float* b2s    = (float*)(smem + B2_OFF);
    float* bhs    = (float*)(smem + BH_OFF);
    float* w2hs   = (float*)(smem + W2H_OFF);

    const int tid  = threadIdx.x;
    const int lane = tid & 63;
    const int wv   = tid >> 6;
    const int ln15 = lane & 15;
    const int ln4  = lane >> 4;
    const int rt = blockIdx.x >> 4;        // 0..15 (32-row tile)
    const int us = blockIdx.x & 15;        // 0..15 (16-unit slice)
    const int r0 = rt * 32;
    const int u0 = us * 16;
    const int eng = wv >> 2;               // 0 = L1 engine, 1 = L2+head engine
    const int wq  = wv & 3;                // engine-wave id
    const int m   = wq >> 1;               // row half (16 rows)
    const int n0  = (wq & 1) * 2;          // first of two 16-col gate tiles

    int* tags1 = flags;            // [16 rt][16 us][4 wq]
    int* tags2 = flags + 1024;

    // ---- one-time weight preload (gate-interleaved row order n = 4*u_local+g) ----
    for (int idx = tid; idx < 64*W1S; idx += 512){
        int n = idx / W1S, c = idx - n*W1S;
        int R = (n & 3)*256 + u0 + (n >> 2);
        float v = 0.f;
        if (c < 10) v = w_ih0[R*10 + c];
        else if (c >= 16 && c < 272) v = w_hh0[R*256 + (c-16)];
        W1l[idx] = (_Float16)v;
    }
    for (int idx = tid; idx < 64*W2S; idx += 512){
        int n = idx / W2S, c = idx - n*W2S;
        int R = (n & 3)*256 + u0 + (n >> 2);
        float v = (c < 256) ? w_ih1[R*256 + c] :
                  ((c < 512) ? w_hh1[R*256 + (c-256)] : 0.f);
        W2l[idx] = (_Float16)v;
    }
    for (int idx = tid; idx < 16*WHS; idx += 512){
        int n = idx / WHS, c = idx - n*WHS;
        float v = (c < 256) ? adv_w1[(u0+n)*256 + c] : 0.f;
        WHl[idx] = (_Float16)v;
    }
    if (tid < 64){
        int R = (tid & 3)*256 + u0 + (tid >> 2);
        b1s[tid] = b_ih0[R] + b_hh0[R];
        b2s[tid] = b_ih1[R] + b_hh1[R];
    }
    if (tid < 16){
        bhs[tid]  = adv_b1[u0 + tid];
        w2hs[tid] = adv_w2[u0 + tid];
    }
    // zero x double-buffer, then stage x(0)
    for (int idx = tid; idx < 1024; idx += 512) XBp[idx] = (_Float16)0.f;
    __syncthreads();
    if (tid < 32){
        const float* xp = x + ((size_t)(r0 + tid)*Tn + 0)*10;
        #pragma unroll
        for (int i = 0; i < 10; ++i) XBp[tid*16 + i] = (_Float16)xp[i];
    }
    __syncthreads();

    // cell states: L1 waves hold c1 for their two tiles, L2 waves hold c2.
    float ca = 0.f, cb = 0.f;
    float* gw = gatesc + wv*(16*GWS);      // wave-private gate scratch

    for (int tau = 0; tau <= Tn + 1; ++tau){
        float xr[10];
        // ===== STAGE: both engines poll + load their h tile concurrently =====
        if (eng == 0){
            if (tau >= 1 && tau <= Tn) poll64(tags1 + rt*64, tau);
            asm volatile("" ::: "memory");
            if (tau <= Tn){
                const int slot = (tau + 3) & 3;         // (tau-1)&3
                const int row = tid >> 3, seg = tid & 7; // tid in [0,256)
                const u64* g = (const u64*)(h1g + (size_t)slot*(Bn*Hn)
                               + (size_t)(r0 + row)*Hn + seg*32);
                u64 v[8];
                #pragma unroll
                for (int q = 0; q < 8; ++q)
                    v[q] = __hip_atomic_load(g + q, __ATOMIC_RELAXED, __HIP_MEMORY_SCOPE_AGENT);
                u64* l = (u64*)(H1l + row*H1S + seg*32);
                #pragma unroll
                for (int q = 0; q < 8; ++q) l[q] = v[q];
            }
        } else {
            if (tau >= 2) poll64(tags2 + rt*64, tau - 1);
            asm volatile("" ::: "memory");
            if (tau >= 1){
                const int slot = (tau + 2) & 3;         // (tau-2)&3
                const int idx = tid - 256;              // [0,256)
                const int row = idx >> 3, seg = idx & 7;
                const u64* g = (const u64*)(h2g + (size_t)slot*(Bn*Hn)
                               + (size_t)(r0 + row)*Hn + seg*32);
                u64 v[8];
                #pragma unroll
                for (int q = 0; q < 8; ++q)
                    v[q] = __hip_atomic_load(g + q, __ATOMIC_RELAXED, __HIP_MEMORY_SCOPE_AGENT);
                u64* l = (u64*)(H2l + row*H2S + seg*32);
                #pragma unroll
                for (int q = 0; q < 8; ++q) l[q] = v[q];
            }
            if (wv == 6 && lane < 32 && tau + 1 < Tn){
                const float* xp = x + ((size_t)(r0 + lane)*Tn + (tau+1))*10;
                #pragma unroll
                for (int i = 0; i < 10; ++i) xr[i] = xp[i];
            }
        }
        __syncthreads();   // stage visible

        // ===== COMPUTE: G1(tau) on waves 0-3 || G2(tau-1)+head(tau-2) on 4-7 =====
        if (eng == 0){
            if (tau < Tn){
                v4f acc0 = {0.f,0.f,0.f,0.f}, acc1 = {0.f,0.f,0.f,0.f};
                {   // k-tile 0: x part (double-buffered, 16 cols incl zero pad)
                    const _Float16* Ax = XBp + (tau & 1)*512 + (m*16 + ln15)*16 + ln4*4;
                    const _Float16* Bx = W1l + (n0*16 + ln15)*W1S + ln4*4;
                    v4h a = *(const v4h*)Ax;
                    acc0 = __builtin_amdgcn_mfma_f32_16x16x16f16(a, *(const v4h*)Bx, acc0, 0,0,0);
                    acc1 = __builtin_amdgcn_mfma_f32_16x16x16f16(a, *(const v4h*)(Bx + 16*W1S), acc1, 0,0,0);
                }
                const _Float16* Ap = H1l + (m*16 + ln15)*H1S + ln4*4;
                const _Float16* Bp = W1l + (n0*16 + ln15)*W1S + 16 + ln4*4;
                #pragma unroll
                for (int k = 0; k < 16; ++k){
                    v4h a = *(const v4h*)(Ap + k*16);
                    acc0 = __builtin_amdgcn_mfma_f32_16x16x16f16(a, *(const v4h*)(Bp + k*16), acc0, 0,0,0);
                    acc1 = __builtin_amdgcn_mfma_f32_16x16x16f16(a, *(const v4h*)(Bp + 16*W1S + k*16), acc1, 0,0,0);
                }
                _Float16* d0 = h1g + (size_t)(tau & 3)*(Bn*Hn)
                             + (size_t)(r0 + m*16 + ln15)*Hn + u0 + n0*4;
                lstm_ew_publish(acc0, gw, b1s, n0,   ca, d0,     ln15, ln4);
                lstm_ew_publish(acc1, gw, b1s, n0+1, cb, d0 + 4, ln15, ln4);
                // release this wave's h1 slice as soon as its stores are at the
                // coherence point — G2/head on other waves keep running.
                asm volatile("s_waitcnt vmcnt(0)" ::: "memory");
                if (lane == 0)
                    __hip_atomic_store(&tags1[rt*64 + us*4 + wq], tau + 1,
                                       __ATOMIC_RELAXED, __HIP_MEMORY_SCOPE_AGENT);
            }
        } else {
            if (wv == 6 && lane < 32 && tau + 1 < Tn){
                _Float16* xd = XBp + ((tau+1) & 1)*512 + lane*16;
                #pragma unroll
                for (int i = 0; i < 10; ++i) xd[i] = (_Float16)xr[i];
            }
            if (tau >= 1 && tau <= Tn){
                v4f acc0 = {0.f,0.f,0.f,0.f}, acc1 = {0.f,0.f,0.f,0.f};
                const _Float16* Ap1 = H1l + (m*16 + ln15)*H1S + ln4*4;
                const _Float16* Ap2 = H2l + (m*16 + ln15)*H2S + ln4*4;
                const _Float16* Bq  = W2l + (n0*16 + ln15)*W2S + ln4*4;
                #pragma unroll
                for (int k = 0; k < 16; ++k){
                    v4h a = *(const v4h*)(Ap1 + k*16);
                    acc0 = __builtin_amdgcn_mfma_f32_16x16x16f16(a, *(const v4h*)(Bq + k*16), acc0, 0,0,0);
                    acc1 = __builtin_amdgcn_mfma_f32_16x16x16f16(a, *(const v4h*)(Bq + 16*W2S + k*16), acc1, 0,0,0);
                }
                #pragma unroll
                for (int k = 0; k < 16; ++k){
                    v4h a = *(const v4h*)(Ap2 + k*16);
                    acc0 = __builtin_amdgcn_mfma_f32_16x16x16f16(a, *(const v4h*)(Bq + 256 + k*16), acc0, 0,0,0);
                    acc1 = __builtin_amdgcn_mfma_f32_16x16x16f16(a, *(const v4h*)(Bq + 16*W2S + 256 + k*16), acc1, 0,0,0);
                }
                _Float16* d0 = h2g + (size_t)((tau + 3) & 3)*(Bn*Hn)
                             + (size_t)(r0 + m*16 + ln15)*Hn + u0 + n0*4;
                lstm_ew_publish(acc0, gw, b2s, n0,   ca, d0,     ln15, ln4);
                lstm_ew_publish(acc1, gw, b2s, n0+1, cb, d0 + 4, ln15, ln4);
                asm volatile("s_waitcnt vmcnt(0)" ::: "memory");
                if (lane == 0)
                    __hip_atomic_store(&tags2[rt*64 + us*4 + wq], tau,
                                       __ATOMIC_RELAXED, __HIP_MEMORY_SCOPE_AGENT);
            }
            if ((wv == 4 || wv == 5) && tau >= 2){
                const int mh = wv & 1;
                v4f acc = {0.f,0.f,0.f,0.f};
                const _Float16* Ap = H2l + (mh*16 + ln15)*H2S + ln4*4;
                const _Float16* Bp = WHl + ln15*WHS + ln4*4;
                #pragma unroll
                for (int k = 0; k < 16; ++k)
                    acc = __builtin_amdgcn_mfma_f32_16x16x16f16(*(const v4h*)(Ap + k*16),
                                                                *(const v4h*)(Bp + k*16), acc, 0, 0, 0);
                float bh = bhs[ln15], w2 = w2hs[ln15];
                float t0 = fmaxf(acc[0] + bh, 0.f) * w2;
                float t1 = fmaxf(acc[1] + bh, 0.f) * w2;
                float t2 = fmaxf(acc[2] + bh, 0.f) * w2;
                float t3 = fmaxf(acc[3] + bh, 0.f) * w2;
                #pragma unroll
                for (int mk = 1; mk <= 8; mk <<= 1){
                    t0 += __shfl_xor(t0, mk, 64);
                    t1 += __shfl_xor(t1, mk, 64);
                    t2 += __shfl_xor(t2, mk, 64);
                    t3 += __shfl_xor(t3, mk, 64);
                }
                if (ln15 == 0){
                    float* sp = scores + (size_t)(tau - 2)*Bn + r0 + mh*16 + ln4*4;
                    atomicAdd(sp + 0, t0);
                    atomicAdd(sp + 1, t1);
                    atomicAdd(sp + 2, t2);
                    atomicAdd(sp + 3, t3);
                }
            }
        }
        __syncthreads();   // compute done; stage(tau+1) may overwrite H1l/H2l
    }
}

// mixed[b] = scores.flat[b*1024 .. b*1024+1023]  (time-major flatten == contiguous)
__global__ __launch_bounds__(256)
void softmax_adv(const float* __restrict__ scores, float* __restrict__ out)
{
    const int b = blockIdx.x, tid = threadIdx.x;
    const int lane = tid & 63, wv = tid >> 6;
    __shared__ float red[4];
    const float4* sp = (const float4*)(scores + (size_t)b*1024);
    float4 v = sp[tid];
    float m = fmaxf(fmaxf(v.x, v.y), fmaxf(v.z, v.w));
    #pragma unroll
    for (int o = 32; o > 0; o >>= 1) m = fmaxf(m, __shfl_xor(m, o, 64));
    if (lane == 0) red[wv] = m;
    __syncthreads();
    m = fmaxf(fmaxf(red[0], red[1]), fmaxf(red[2], red[3]));
    __syncthreads();
    float e0 = __expf(v.x - m), e1 = __expf(v.y - m);
    float e2 = __expf(v.z - m), e3 = __expf(v.w - m);
    float s = e0 + e1 + e2 + e3;
    #pragma unroll
    for (int o = 32; o > 0; o >>= 1) s += __shfl_xor(s, o, 64);
    if (lane == 0) red[wv] = s;
    __syncthreads();
    s = red[0] + red[1] + red[2] + red[3];
    float inv = 1.0f / s;
    float4 o4; o4.x = e0*inv; o4.y = e1*inv; o4.z = e2*inv; o4.w = e3*inv;
    ((float4*)(out + (size_t)b*1024))[tid] = o4;
}

extern "C" void kernel_launch(void* const* d_in, const int* in_sizes, int n_in,
                              void* d_out, int out_size, void* d_ws, size_t ws_size,
                              hipStream_t stream)
{
    (void)in_sizes; (void)n_in; (void)out_size; (void)ws_size;
    const float* x      = (const float*)d_in[0];
    const float* w_ih0  = (const float*)d_in[1];
    const float* w_hh0  = (const float*)d_in[2];
    const float* b_ih0  = (const float*)d_in[3];
    const float* b_hh0  = (const float*)d_in[4];
    const float* w_ih1  = (const float*)d_in[5];
    const float* w_hh1  = (const float*)d_in[6];
    const float* b_ih1  = (const float*)d_in[7];
    const float* b_hh1  = (const float*)d_in[8];
    const float* adv_w1 = (const float*)d_in[9];
    const float* adv_b1 = (const float*)d_in[10];
    const float* adv_w2 = (const float*)d_in[11];
    // adv_w2 bias (d_in[12]) cancels in softmax — unused.

    float*    scores = (float*)((char*)d_ws + SCORES_OFF);
    _Float16* h1g    = (_Float16*)((char*)d_ws + H1G_OFF);
    _Float16* h2g    = (_Float16*)((char*)d_ws + H2G_OFF);
    int*      flags  = (int*)((char*)d_ws + FLAG_OFF);

    hipMemsetAsync(d_ws, 0, WS_USED, stream);
    hipFuncSetAttribute((const void*)lstm_pipe,
                        hipFuncAttributeMaxDynamicSharedMemorySize, LDS_TOTAL);

    hipLaunchKernelGGL(lstm_pipe, dim3(256), dim3(512), LDS_TOTAL, stream,
                       x, w_ih0, w_hh0, b_ih0, b_hh0, w_ih1, w_hh1, b_ih1, b_hh1,
                       adv_w1, adv_b1, adv_w2, scores, h1g, h2g, flags);
    hipLaunchKernelGGL(softmax_adv, dim3(512), dim3(256), 0, stream,
                       scores, (float*)d_out);
}

// Round 6
// 5885.975 us; speedup vs baseline: 1.1559x; 1.1559x over previous
//
#include <hip/hip_runtime.h>
#include <cstdint>
#include <cstddef>

// Problem constants
#define Tn 1024
#define Bn 512
#define Hn 256

// Partition: 256 blocks = 16 row-tiles (32 rows) x 16 unit-slices (16 units)
// Waves 0-3 = layer-1 engine, waves 4-7 = layer-2 + head engine.
// KEY CHANGE vs R1 baseline: gate-weight B-fragments (time-invariant) live in
// per-wave VGPRs (v4h W[64], statically indexed), not LDS. Removes ~75% of the
// per-timestep LDS reads + their bank conflicts. Exchange protocol = R1 verbatim
// (agent-scope atomics, per-wave tags) — the proven-correct path.
#define H1S 264
#define H2S 264
#define WHS 264
#define GWS 20    // per-wave gate scratch row stride (floats)

#define H1_OFF  0
#define H2_OFF  (H1_OFF + 32*H1S*2)      // 16896
#define XB_OFF  (H2_OFF + 32*H2S*2)      // 33792
#define WH_OFF  (XB_OFF + 2*32*16*2)     // 35840
#define GW_OFF  (WH_OFF + 16*WHS*2)      // 44288
#define B1_OFF  (GW_OFF + 8*16*GWS*4)    // 54528
#define B2_OFF  (B1_OFF + 64*4)
#define BH_OFF  (B2_OFF + 64*4)
#define W2H_OFF (BH_OFF + 16*4)
// pad > 80 KiB so only 1 block/CU is resident (protocol liveness margin + solo LDS)
#define LDS_TOTAL 90112

// ws layout (bytes)
#define SCORES_OFF 0                      // [1024][512] f32 = 2MB
#define H1G_OFF  (2*1024*1024)            // 4 slots x [512][256] fp16 = 1MB
#define H2G_OFF  (3*1024*1024)            // 1MB
#define FLAG_OFF (4*1024*1024)            // tags1[1024], tags2 at +1024 ints
#define WS_USED  (4*1024*1024 + 8192)

typedef _Float16 v4h __attribute__((ext_vector_type(4)));
typedef float    v4f __attribute__((ext_vector_type(4)));
typedef unsigned long long u64;

__device__ inline float sigm(float x){ return 1.0f/(1.0f + __expf(-x)); }
__device__ inline float tanh_f(float x){ return 1.0f - 2.0f/(1.0f + __expf(2.0f*x)); }

__device__ inline v4h cvt4(float4 a){
    v4h f; f[0]=(_Float16)a.x; f[1]=(_Float16)a.y; f[2]=(_Float16)a.z; f[3]=(_Float16)a.w;
    return f;
}

// 64 per-producer-wave tags per row-tile group: lane i watches tag i.
__device__ inline void poll64(const int* tags, int tgt){
    int idx = threadIdx.x & 63;
    while (true){
        int t = __hip_atomic_load(&tags[idx], __ATOMIC_RELAXED, __HIP_MEMORY_SCOPE_AGENT);
        if (__ballot(t < tgt) == 0ull) break;
        __builtin_amdgcn_s_sleep(1);
    }
}

// LSTM elementwise + publish for one 16x16 gate tile (tile-local col = 4*unit+gate).
__device__ __forceinline__ void lstm_ew_publish(v4f acc, float* gw, const float* bs,
                                                int n, float& c, _Float16* dst,
                                                int ln15, int ln4)
{
    #pragma unroll
    for (int r = 0; r < 4; ++r) gw[(ln4*4 + r)*GWS + ln15] = acc[r];
    asm volatile("s_waitcnt lgkmcnt(0)" ::: "memory");
    v4f g4 = *(const v4f*)(gw + ln15*GWS + ln4*4);
    asm volatile("s_waitcnt lgkmcnt(0)" ::: "memory");
    v4f bb = *(const v4f*)(bs + n*16 + ln4*4);
    float gi = sigm(g4.x + bb.x), gf = sigm(g4.y + bb.y);
    float gg = tanh_f(g4.z + bb.z), go = sigm(g4.w + bb.w);
    c = gf*c + gi*gg;
    float hn = go * tanh_f(c);
    union { _Float16 h; unsigned short u; } cvt; cvt.h = (_Float16)hn;
    unsigned v32 = cvt.u;
    unsigned p16 = (unsigned)__shfl_xor((int)v32, 16, 64);
    unsigned lo32 = v32 | (p16 << 16);
    unsigned hi32 = (unsigned)__shfl_xor((int)lo32, 32, 64);
    if (ln4 == 0){
        u64 pk = (u64)lo32 | ((u64)hi32 << 32);
        __hip_atomic_store((u64*)dst, pk, __ATOMIC_RELAXED, __HIP_MEMORY_SCOPE_AGENT);
    }
}

__global__ __launch_bounds__(512)
void lstm_pipe(const float* __restrict__ x,
               const float* __restrict__ w_ih0, const float* __restrict__ w_hh0,
               const float* __restrict__ b_ih0, const float* __restrict__ b_hh0,
               const float* __restrict__ w_ih1, const float* __restrict__ w_hh1,
               const float* __restrict__ b_ih1, const float* __restrict__ b_hh1,
               const float* __restrict__ adv_w1, const float* __restrict__ adv_b1,
               const float* __restrict__ adv_w2,
               float* __restrict__ scores, _Float16* __restrict__ h1g,
               _Float16* __restrict__ h2g, int* __restrict__ flags)
{
    extern __shared__ char smem[];
    _Float16* H1l = (_Float16*)(smem + H1_OFF);
    _Float16* H2l = (_Float16*)(smem + H2_OFF);
    _Float16* XBp = (_Float16*)(smem + XB_OFF);
    _Float16* WHl = (_Float16*)(smem + WH_OFF);
    float* gatesc = (float*)(smem + GW_OFF);
    float* b1s    = (float*)(smem + B1_OFF);
    float* b2s    = (float*)(smem + B2_OFF);
    float* bhs    = (float*)(smem + BH_OFF);
    float* w2hs   = (float*)(smem + W2H_OFF);

    const int tid  = threadIdx.x;
    const int lane = tid & 63;
    const int wv   = tid >> 6;
    const int ln15 = lane & 15;
    const int ln4  = lane >> 4;
    const int rt = blockIdx.x >> 4;        // 0..15 (32-row tile)
    const int us = blockIdx.x & 15;        // 0..15 (16-unit slice)
    const int r0 = rt * 32;
    const int u0 = us * 16;
    const int eng = wv >> 2;               // 0 = L1 engine, 1 = L2+head engine
    const int wq  = wv & 3;                // engine-wave id
    const int m   = wq >> 1;               // row half (16 rows)
    const int n0  = (wq & 1) * 2;          // first of two 16-col gate tiles

    int* tags1 = flags;            // [16 rt][16 us][4 wq]
    int* tags2 = flags + 1024;

    // ---- one-time weight fragments -> VGPRs (gate-interleaved row N=4*u+g) ----
    // This wave owns gate-rows N0 = n0*16+ln15 and N1 = N0+16; lane quarter ln4.
    const int N0i = n0*16 + ln15;
    const int R0 = (N0i & 3)*256 + u0 + (N0i >> 2);
    const int N1i = N0i + 16;
    const int R1 = (N1i & 3)*256 + u0 + (N1i >> 2);
    v4h W[64];
    if (eng == 0){
        // W[0..1]: x-part (cols ln4*4+j, zero-pad >=10); W[2+k]/W[18+k]: hh-part
        #pragma unroll
        for (int t = 0; t < 2; ++t){
            const int R = t ? R1 : R0;
            v4h f;
            #pragma unroll
            for (int j = 0; j < 4; ++j){
                int c = ln4*4 + j;
                f[j] = (_Float16)((c < 10) ? w_ih0[R*10 + c] : 0.f);
            }
            W[t] = f;
        }
        #pragma unroll
        for (int k = 0; k < 16; ++k){
            float4 a0 = *(const float4*)(w_hh0 + (size_t)R0*256 + k*16 + ln4*4);
            float4 a1 = *(const float4*)(w_hh0 + (size_t)R1*256 + k*16 + ln4*4);
            W[2+k]  = cvt4(a0);
            W[18+k] = cvt4(a1);
        }
    } else {
        // W[k]/W[16+k]: w_ih1 rows R0/R1; W[32+k]/W[48+k]: w_hh1 rows R0/R1
        #pragma unroll
        for (int k = 0; k < 16; ++k){
            float4 a0 = *(const float4*)(w_ih1 + (size_t)R0*256 + k*16 + ln4*4);
            float4 a1 = *(const float4*)(w_ih1 + (size_t)R1*256 + k*16 + ln4*4);
            float4 b0 = *(const float4*)(w_hh1 + (size_t)R0*256 + k*16 + ln4*4);
            float4 b1 = *(const float4*)(w_hh1 + (size_t)R1*256 + k*16 + ln4*4);
            W[k]    = cvt4(a0);
            W[16+k] = cvt4(a1);
            W[32+k] = cvt4(b0);
            W[48+k] = cvt4(b1);
        }
    }

    // ---- LDS one-time: head weights, biases, x buffer ----
    for (int idx = tid; idx < 16*WHS; idx += 512){
        int n = idx / WHS, c = idx - n*WHS;
        float v = (c < 256) ? adv_w1[(u0+n)*256 + c] : 0.f;
        WHl[idx] = (_Float16)v;
    }
    if (tid < 64){
        int R = (tid & 3)*256 + u0 + (tid >> 2);
        b1s[tid] = b_ih0[R] + b_hh0[R];
        b2s[tid] = b_ih1[R] + b_hh1[R];
    }
    if (tid < 16){
        bhs[tid]  = adv_b1[u0 + tid];
        w2hs[tid] = adv_w2[u0 + tid];
    }
    // zero x double-buffer, then stage x(0)
    for (int idx = tid; idx < 1024; idx += 512) XBp[idx] = (_Float16)0.f;
    __syncthreads();
    if (tid < 32){
        const float* xp = x + ((size_t)(r0 + tid)*Tn + 0)*10;
        #pragma unroll
        for (int i = 0; i < 10; ++i) XBp[tid*16 + i] = (_Float16)xp[i];
    }
    __syncthreads();

    // cell states: each wave holds c for its two gate tiles.
    float ca = 0.f, cb = 0.f;
    float* gw = gatesc + wv*(16*GWS);      // wave-private gate scratch

    for (int tau = 0; tau <= Tn + 1; ++tau){
        float xr[10];
        // ===== STAGE: both engines poll + load their h tile concurrently =====
        if (eng == 0){
            if (tau >= 1 && tau <= Tn) poll64(tags1 + rt*64, tau);
            asm volatile("" ::: "memory");
            if (tau <= Tn){
                const int slot = (tau + 3) & 3;          // (tau-1)&3
                const int row = tid >> 3, seg = tid & 7; // tid in [0,256)
                const u64* g = (const u64*)(h1g + (size_t)slot*(Bn*Hn)
                               + (size_t)(r0 + row)*Hn + seg*32);
                u64 v[8];
                #pragma unroll
                for (int q = 0; q < 8; ++q)
                    v[q] = __hip_atomic_load(g + q, __ATOMIC_RELAXED, __HIP_MEMORY_SCOPE_AGENT);
                u64* l = (u64*)(H1l + row*H1S + seg*32);
                #pragma unroll
                for (int q = 0; q < 8; ++q) l[q] = v[q];
            }
        } else {
            if (tau >= 2) poll64(tags2 + rt*64, tau - 1);
            asm volatile("" ::: "memory");
            if (tau >= 1){
                const int slot = (tau + 2) & 3;          // (tau-2)&3
                const int idx = tid - 256;               // [0,256)
                const int row = idx >> 3, seg = idx & 7;
                const u64* g = (const u64*)(h2g + (size_t)slot*(Bn*Hn)
                               + (size_t)(r0 + row)*Hn + seg*32);
                u64 v[8];
                #pragma unroll
                for (int q = 0; q < 8; ++q)
                    v[q] = __hip_atomic_load(g + q, __ATOMIC_RELAXED, __HIP_MEMORY_SCOPE_AGENT);
                u64* l = (u64*)(H2l + row*H2S + seg*32);
                #pragma unroll
                for (int q = 0; q < 8; ++q) l[q] = v[q];
            }
            if (wv == 6 && lane < 32 && tau + 1 < Tn){
                const float* xp = x + ((size_t)(r0 + lane)*Tn + (tau+1))*10;
                #pragma unroll
                for (int i = 0; i < 10; ++i) xr[i] = xp[i];
            }
        }
        __syncthreads();   // stage visible

        // ===== COMPUTE: G1(tau) on waves 0-3 || G2(tau-1)+head(tau-2) on 4-7 =====
        if (eng == 0){
            if (tau < Tn){
                v4f acc0 = {0.f,0.f,0.f,0.f}, acc1 = {0.f,0.f,0.f,0.f};
                {   // k-tile 0: x part (double-buffered, 16 cols incl zero pad)
                    v4h a = *(const v4h*)(XBp + (tau & 1)*512 + (m*16 + ln15)*16 + ln4*4);
                    acc0 = __builtin_amdgcn_mfma_f32_16x16x16f16(a, W[0], acc0, 0,0,0);
                    acc1 = __builtin_amdgcn_mfma_f32_16x16x16f16(a, W[1], acc1, 0,0,0);
                }
                const _Float16* Ap = H1l + (m*16 + ln15)*H1S + ln4*4;
                #pragma unroll
                for (int k = 0; k < 16; ++k){
                    v4h a = *(const v4h*)(Ap + k*16);
                    acc0 = __builtin_amdgcn_mfma_f32_16x16x16f16(a, W[2+k],  acc0, 0,0,0);
                    acc1 = __builtin_amdgcn_mfma_f32_16x16x16f16(a, W[18+k], acc1, 0,0,0);
                }
                _Float16* d0 = h1g + (size_t)(tau & 3)*(Bn*Hn)
                             + (size_t)(r0 + m*16 + ln15)*Hn + u0 + n0*4;
                lstm_ew_publish(acc0, gw, b1s, n0,   ca, d0,     ln15, ln4);
                lstm_ew_publish(acc1, gw, b1s, n0+1, cb, d0 + 4, ln15, ln4);
                asm volatile("s_waitcnt vmcnt(0)" ::: "memory");
                if (lane == 0)
                    __hip_atomic_store(&tags1[rt*64 + us*4 + wq], tau + 1,
                                       __ATOMIC_RELAXED, __HIP_MEMORY_SCOPE_AGENT);
            }
        } else {
            if (wv == 6 && lane < 32 && tau + 1 < Tn){
                _Float16* xd = XBp + ((tau+1) & 1)*512 + lane*16;
                #pragma unroll
                for (int i = 0; i < 10; ++i) xd[i] = (_Float16)xr[i];
            }
            if (tau >= 1 && tau <= Tn){
                v4f acc0 = {0.f,0.f,0.f,0.f}, acc1 = {0.f,0.f,0.f,0.f};
                const _Float16* Ap1 = H1l + (m*16 + ln15)*H1S + ln4*4;
                const _Float16* Ap2 = H2l + (m*16 + ln15)*H2S + ln4*4;
                #pragma unroll
                for (int k = 0; k < 16; ++k){
                    v4h a = *(const v4h*)(Ap1 + k*16);
                    acc0 = __builtin_amdgcn_mfma_f32_16x16x16f16(a, W[k],    acc0, 0,0,0);
                    acc1 = __builtin_amdgcn_mfma_f32_16x16x16f16(a, W[16+k], acc1, 0,0,0);
                }
                #pragma unroll
                for (int k = 0; k < 16; ++k){
                    v4h a = *(const v4h*)(Ap2 + k*16);
                    acc0 = __builtin_amdgcn_mfma_f32_16x16x16f16(a, W[32+k], acc0, 0,0,0);
                    acc1 = __builtin_amdgcn_mfma_f32_16x16x16f16(a, W[48+k], acc1, 0,0,0);
                }
                _Float16* d0 = h2g + (size_t)((tau + 3) & 3)*(Bn*Hn)
                             + (size_t)(r0 + m*16 + ln15)*Hn + u0 + n0*4;
                lstm_ew_publish(acc0, gw, b2s, n0,   ca, d0,     ln15, ln4);
                lstm_ew_publish(acc1, gw, b2s, n0+1, cb, d0 + 4, ln15, ln4);
                asm volatile("s_waitcnt vmcnt(0)" ::: "memory");
                if (lane == 0)
                    __hip_atomic_store(&tags2[rt*64 + us*4 + wq], tau,
                                       __ATOMIC_RELAXED, __HIP_MEMORY_SCOPE_AGENT);
            }
            if ((wv == 4 || wv == 5) && tau >= 2){
                const int mh = wv & 1;
                v4f acc = {0.f,0.f,0.f,0.f};
                const _Float16* Ap = H2l + (mh*16 + ln15)*H2S + ln4*4;
                const _Float16* Bp = WHl + ln15*WHS + ln4*4;
                #pragma unroll
                for (int k = 0; k < 16; ++k)
                    acc = __builtin_amdgcn_mfma_f32_16x16x16f16(*(const v4h*)(Ap + k*16),
                                                                *(const v4h*)(Bp + k*16), acc, 0, 0, 0);
                float bh = bhs[ln15], w2 = w2hs[ln15];
                float t0 = fmaxf(acc[0] + bh, 0.f) * w2;
                float t1 = fmaxf(acc[1] + bh, 0.f) * w2;
                float t2 = fmaxf(acc[2] + bh, 0.f) * w2;
                float t3 = fmaxf(acc[3] + bh, 0.f) * w2;
                #pragma unroll
                for (int mk = 1; mk <= 8; mk <<= 1){
                    t0 += __shfl_xor(t0, mk, 64);
                    t1 += __shfl_xor(t1, mk, 64);
                    t2 += __shfl_xor(t2, mk, 64);
                    t3 += __shfl_xor(t3, mk, 64);
                }
                if (ln15 == 0){
                    float* sp = scores + (size_t)(tau - 2)*Bn + r0 + mh*16 + ln4*4;
                    atomicAdd(sp + 0, t0);
                    atomicAdd(sp + 1, t1);
                    atomicAdd(sp + 2, t2);
                    atomicAdd(sp + 3, t3);
                }
            }
        }
        __syncthreads();   // compute done; stage(tau+1) may overwrite H1l/H2l
    }
}

// mixed[b] = scores.flat[b*1024 .. b*1024+1023]  (time-major flatten == contiguous)
__global__ __launch_bounds__(256)
void softmax_adv(const float* __restrict__ scores, float* __restrict__ out)
{
    const int b = blockIdx.x, tid = threadIdx.x;
    const int lane = tid & 63, wv = tid >> 6;
    __shared__ float red[4];
    const float4* sp = (const float4*)(scores + (size_t)b*1024);
    float4 v = sp[tid];
    float m = fmaxf(fmaxf(v.x, v.y), fmaxf(v.z, v.w));
    #pragma unroll
    for (int o = 32; o > 0; o >>= 1) m = fmaxf(m, __shfl_xor(m, o, 64));
    if (lane == 0) red[wv] = m;
    __syncthreads();
    m = fmaxf(fmaxf(red[0], red[1]), fmaxf(red[2], red[3]));
    __syncthreads();
    float e0 = __expf(v.x - m), e1 = __expf(v.y - m);
    float e2 = __expf(v.z - m), e3 = __expf(v.w - m);
    float s = e0 + e1 + e2 + e3;
    #pragma unroll
    for (int o = 32; o > 0; o >>= 1) s += __shfl_xor(s, o, 64);
    if (lane == 0) red[wv] = s;
    __syncthreads();
    s = red[0] + red[1] + red[2] + red[3];
    float inv = 1.0f / s;
    float4 o4; o4.x = e0*inv; o4.y = e1*inv; o4.z = e2*inv; o4.w = e3*inv;
    ((float4*)(out + (size_t)b*1024))[tid] = o4;
}

extern "C" void kernel_launch(void* const* d_in, const int* in_sizes, int n_in,
                              void* d_out, int out_size, void* d_ws, size_t ws_size,
                              hipStream_t stream)
{
    (void)in_sizes; (void)n_in; (void)out_size; (void)ws_size;
    const float* x      = (const float*)d_in[0];
    const float* w_ih0  = (const float*)d_in[1];
    const float* w_hh0  = (const float*)d_in[2];
    const float* b_ih0  = (const float*)d_in[3];
    const float* b_hh0  = (const float*)d_in[4];
    const float* w_ih1  = (const float*)d_in[5];
    const float* w_hh1  = (const float*)d_in[6];
    const float* b_ih1  = (const float*)d_in[7];
    const float* b_hh1  = (const float*)d_in[8];
    const float* adv_w1 = (const float*)d_in[9];
    const float* adv_b1 = (const float*)d_in[10];
    const float* adv_w2 = (const float*)d_in[11];
    // adv_w2 bias (d_in[12]) cancels in softmax — unused.

    float*    scores = (float*)((char*)d_ws + SCORES_OFF);
    _Float16* h1g    = (_Float16*)((char*)d_ws + H1G_OFF);
    _Float16* h2g    = (_Float16*)((char*)d_ws + H2G_OFF);
    int*      flags  = (int*)((char*)d_ws + FLAG_OFF);

    hipMemsetAsync(d_ws, 0, WS_USED, stream);
    hipFuncSetAttribute((const void*)lstm_pipe,
                        hipFuncAttributeMaxDynamicSharedMemorySize, LDS_TOTAL);

    hipLaunchKernelGGL(lstm_pipe, dim3(256), dim3(512), LDS_TOTAL, stream,
                       x, w_ih0, w_hh0, b_ih0, b_hh0, w_ih1, w_hh1, b_ih1, b_hh1,
                       adv_w1, adv_b1, adv_w2, scores, h1g, h2g, flags);
    hipLaunchKernelGGL(softmax_adv, dim3(512), dim3(256), 0, stream,
                       scores, (float*)d_out);
}

// Round 7
// 4367.126 us; speedup vs baseline: 1.5579x; 1.3478x over previous
//
#include <hip/hip_runtime.h>
#include <cstdint>
#include <cstddef>

// Problem constants
#define Tn 1024
#define Bn 512
#define Hn 256

// Partition: 256 blocks = 16 row-tiles (32 rows) x 16 unit-slices (16 units)
// Waves 0-3 = layer-1 engine, waves 4-7 = layer-2 + head engine.
// Weights in VGPRs (R6, verified). This round: coalesced 16B sc0+sc1 staging
// (4x fewer MALL requests) + single-wave polling per engine (4x fewer tag reads).
// Publish path unchanged: agent-scope atomics + vmcnt(0) + agent tag store.
#define H1S 264
#define H2S 264
#define WHS 264
#define GWS 20    // per-wave gate scratch row stride (floats)

#define H1_OFF  0
#define H2_OFF  (H1_OFF + 32*H1S*2)      // 16896
#define XB_OFF  (H2_OFF + 32*H2S*2)      // 33792
#define WH_OFF  (XB_OFF + 2*32*16*2)     // 35840
#define GW_OFF  (WH_OFF + 16*WHS*2)      // 44288
#define B1_OFF  (GW_OFF + 8*16*GWS*4)    // 54528
#define B2_OFF  (B1_OFF + 64*4)
#define BH_OFF  (B2_OFF + 64*4)
#define W2H_OFF (BH_OFF + 16*4)
// pad > 80 KiB so only 1 block/CU is resident
#define LDS_TOTAL 90112

// ws layout (bytes)
#define SCORES_OFF 0                      // [1024][512] f32 = 2MB
#define H1G_OFF  (2*1024*1024)            // 4 slots x [512][256] fp16 = 1MB
#define H2G_OFF  (3*1024*1024)            // 1MB
#define FLAG_OFF (4*1024*1024)            // tags1[1024], tags2 at +1024 ints
#define WS_USED  (4*1024*1024 + 8192)

typedef _Float16 v4h __attribute__((ext_vector_type(4)));
typedef float    v4f __attribute__((ext_vector_type(4)));
typedef unsigned int u32x4 __attribute__((ext_vector_type(4)));
typedef unsigned long long u64;

__device__ inline float sigm(float x){ return 1.0f/(1.0f + __expf(-x)); }
__device__ inline float tanh_f(float x){ return 1.0f - 2.0f/(1.0f + __expf(2.0f*x)); }

__device__ inline v4h cvt4(float4 a){
    v4h f; f[0]=(_Float16)a.x; f[1]=(_Float16)a.y; f[2]=(_Float16)a.z; f[3]=(_Float16)a.w;
    return f;
}

// 64 per-producer-wave tags per row-tile group: lane i watches tag i.
__device__ inline void poll64(const int* tags, int tgt){
    int idx = threadIdx.x & 63;
    while (true){
        int t = __hip_atomic_load(&tags[idx], __ATOMIC_RELAXED, __HIP_MEMORY_SCOPE_AGENT);
        if (__ballot(t < tgt) == 0ull) break;
        __builtin_amdgcn_s_sleep(1);
    }
}

// Coalesced 16KB tile stage: thread t (0..255) loads 4x16B at o = j*4096 + t*16
// (per-instruction lane-contiguous -> 64B-sector-perfect), sc0+sc1 = L1/L2 bypass
// (>= agent scope). Safe vs tearing: all 64 producer tags polled before any read,
// producers vmcnt(0)-drain before tagging. LDS write applies 528B row stride.
#define LADDR(oo) ( (size_t)(((oo)>>9)*528 + ((oo)&511)) )
__device__ __forceinline__ void stage_tile(const char* gbase, char* lbase, int t){
    u32x4 q0,q1,q2,q3;
    const char* p0 = gbase + t*16;
    const char* p1 = p0 + 4096;
    const char* p2 = p0 + 8192;
    const char* p3 = p0 + 12288;
    asm volatile("global_load_dwordx4 %0, %1, off sc0 sc1" : "=v"(q0) : "v"(p0));
    asm volatile("global_load_dwordx4 %0, %1, off sc0 sc1" : "=v"(q1) : "v"(p1));
    asm volatile("global_load_dwordx4 %0, %1, off sc0 sc1" : "=v"(q2) : "v"(p2));
    asm volatile("global_load_dwordx4 %0, %1, off sc0 sc1" : "=v"(q3) : "v"(p3));
    asm volatile("s_waitcnt vmcnt(0)"
                 : "+v"(q0), "+v"(q1), "+v"(q2), "+v"(q3) :: "memory");
    const int o = t*16;
    *(u32x4*)(lbase + LADDR(o))         = q0;
    *(u32x4*)(lbase + LADDR(o + 4096))  = q1;
    *(u32x4*)(lbase + LADDR(o + 8192))  = q2;
    *(u32x4*)(lbase + LADDR(o + 12288)) = q3;
}

// LSTM elementwise + publish for one 16x16 gate tile (tile-local col = 4*unit+gate).
__device__ __forceinline__ void lstm_ew_publish(v4f acc, float* gw, const float* bs,
                                                int n, float& c, _Float16* dst,
                                                int ln15, int ln4)
{
    #pragma unroll
    for (int r = 0; r < 4; ++r) gw[(ln4*4 + r)*GWS + ln15] = acc[r];
    asm volatile("s_waitcnt lgkmcnt(0)" ::: "memory");
    v4f g4 = *(const v4f*)(gw + ln15*GWS + ln4*4);
    asm volatile("s_waitcnt lgkmcnt(0)" ::: "memory");
    v4f bb = *(const v4f*)(bs + n*16 + ln4*4);
    float gi = sigm(g4.x + bb.x), gf = sigm(g4.y + bb.y);
    float gg = tanh_f(g4.z + bb.z), go = sigm(g4.w + bb.w);
    c = gf*c + gi*gg;
    float hn = go * tanh_f(c);
    union { _Float16 h; unsigned short u; } cvt; cvt.h = (_Float16)hn;
    unsigned v32 = cvt.u;
    unsigned p16 = (unsigned)__shfl_xor((int)v32, 16, 64);
    unsigned lo32 = v32 | (p16 << 16);
    unsigned hi32 = (unsigned)__shfl_xor((int)lo32, 32, 64);
    if (ln4 == 0){
        u64 pk = (u64)lo32 | ((u64)hi32 << 32);
        __hip_atomic_store((u64*)dst, pk, __ATOMIC_RELAXED, __HIP_MEMORY_SCOPE_AGENT);
    }
}

__global__ __launch_bounds__(512)
void lstm_pipe(const float* __restrict__ x,
               const float* __restrict__ w_ih0, const float* __restrict__ w_hh0,
               const float* __restrict__ b_ih0, const float* __restrict__ b_hh0,
               const float* __restrict__ w_ih1, const float* __restrict__ w_hh1,
               const float* __restrict__ b_ih1, const float* __restrict__ b_hh1,
               const float* __restrict__ adv_w1, const float* __restrict__ adv_b1,
               const float* __restrict__ adv_w2,
               float* __restrict__ scores, _Float16* __restrict__ h1g,
               _Float16* __restrict__ h2g, int* __restrict__ flags)
{
    extern __shared__ char smem[];
    _Float16* H1l = (_Float16*)(smem + H1_OFF);
    _Float16* H2l = (_Float16*)(smem + H2_OFF);
    _Float16* XBp = (_Float16*)(smem + XB_OFF);
    _Float16* WHl = (_Float16*)(smem + WH_OFF);
    float* gatesc = (float*)(smem + GW_OFF);
    float* b1s    = (float*)(smem + B1_OFF);
    float* b2s    = (float*)(smem + B2_OFF);
    float* bhs    = (float*)(smem + BH_OFF);
    float* w2hs   = (float*)(smem + W2H_OFF);

    const int tid  = threadIdx.x;
    const int lane = tid & 63;
    const int wv   = tid >> 6;
    const int ln15 = lane & 15;
    const int ln4  = lane >> 4;
    const int rt = blockIdx.x >> 4;        // 0..15 (32-row tile)
    const int us = blockIdx.x & 15;        // 0..15 (16-unit slice)
    const int r0 = rt * 32;
    const int u0 = us * 16;
    const int eng = wv >> 2;               // 0 = L1 engine, 1 = L2+head engine
    const int wq  = wv & 3;                // engine-wave id
    const int m   = wq >> 1;               // row half (16 rows)
    const int n0  = (wq & 1) * 2;          // first of two 16-col gate tiles

    int* tags1 = flags;            // [16 rt][16 us][4 wq]
    int* tags2 = flags + 1024;

    // ---- one-time weight fragments -> VGPRs (gate-interleaved row N=4*u+g) ----
    const int N0i = n0*16 + ln15;
    const int R0 = (N0i & 3)*256 + u0 + (N0i >> 2);
    const int N1i = N0i + 16;
    const int R1 = (N1i & 3)*256 + u0 + (N1i >> 2);
    v4h W[64];
    if (eng == 0){
        #pragma unroll
        for (int t = 0; t < 2; ++t){
            const int R = t ? R1 : R0;
            v4h f;
            #pragma unroll
            for (int j = 0; j < 4; ++j){
                int c = ln4*4 + j;
                f[j] = (_Float16)((c < 10) ? w_ih0[R*10 + c] : 0.f);
            }
            W[t] = f;
        }
        #pragma unroll
        for (int k = 0; k < 16; ++k){
            float4 a0 = *(const float4*)(w_hh0 + (size_t)R0*256 + k*16 + ln4*4);
            float4 a1 = *(const float4*)(w_hh0 + (size_t)R1*256 + k*16 + ln4*4);
            W[2+k]  = cvt4(a0);
            W[18+k] = cvt4(a1);
        }
    } else {
        #pragma unroll
        for (int k = 0; k < 16; ++k){
            float4 a0 = *(const float4*)(w_ih1 + (size_t)R0*256 + k*16 + ln4*4);
            float4 a1 = *(const float4*)(w_ih1 + (size_t)R1*256 + k*16 + ln4*4);
            float4 b0 = *(const float4*)(w_hh1 + (size_t)R0*256 + k*16 + ln4*4);
            float4 b1 = *(const float4*)(w_hh1 + (size_t)R1*256 + k*16 + ln4*4);
            W[k]    = cvt4(a0);
            W[16+k] = cvt4(a1);
            W[32+k] = cvt4(b0);
            W[48+k] = cvt4(b1);
        }
    }

    // ---- LDS one-time: head weights, biases, x buffer ----
    for (int idx = tid; idx < 16*WHS; idx += 512){
        int n = idx / WHS, c = idx - n*WHS;
        float v = (c < 256) ? adv_w1[(u0+n)*256 + c] : 0.f;
        WHl[idx] = (_Float16)v;
    }
    if (tid < 64){
        int R = (tid & 3)*256 + u0 + (tid >> 2);
        b1s[tid] = b_ih0[R] + b_hh0[R];
        b2s[tid] = b_ih1[R] + b_hh1[R];
    }
    if (tid < 16){
        bhs[tid]  = adv_b1[u0 + tid];
        w2hs[tid] = adv_w2[u0 + tid];
    }
    // zero x double-buffer, then stage x(0)
    for (int idx = tid; idx < 1024; idx += 512) XBp[idx] = (_Float16)0.f;
    __syncthreads();
    if (tid < 32){
        const float* xp = x + ((size_t)(r0 + tid)*Tn + 0)*10;
        #pragma unroll
        for (int i = 0; i < 10; ++i) XBp[tid*16 + i] = (_Float16)xp[i];
    }
    __syncthreads();

    // cell states: each wave holds c for its two gate tiles.
    float ca = 0.f, cb = 0.f;
    float* gw = gatesc + wv*(16*GWS);      // wave-private gate scratch

    for (int tau = 0; tau <= Tn + 1; ++tau){
        float xr[10];
        // ===== x prefetch issue (independent of polls) =====
        if (wv == 6 && lane < 32 && tau + 1 < Tn){
            const float* xp = x + ((size_t)(r0 + lane)*Tn + (tau+1))*10;
            #pragma unroll
            for (int i = 0; i < 10; ++i) xr[i] = xp[i];
        }
        // ===== POLL: one wave per engine =====
        if (wv == 0 && tau >= 1 && tau <= Tn) poll64(tags1 + rt*64, tau);
        if (wv == 4 && tau >= 2)              poll64(tags2 + rt*64, tau - 1);
        asm volatile("" ::: "memory");
        __syncthreads();   // A0: tags satisfied for both engines

        // ===== STAGE: coalesced 16B sc0+sc1 loads -> LDS =====
        if (eng == 0){
            if (tau <= Tn){
                const int slot = (tau + 3) & 3;          // (tau-1)&3
                stage_tile((const char*)(h1g + (size_t)slot*(Bn*Hn) + (size_t)r0*Hn),
                           (char*)H1l, tid);             // t in [0,256)
            }
        } else {
            if (tau >= 1){
                const int slot = (tau + 2) & 3;          // (tau-2)&3
                stage_tile((const char*)(h2g + (size_t)slot*(Bn*Hn) + (size_t)r0*Hn),
                           (char*)H2l, tid - 256);
            }
        }
        __syncthreads();   // A: staged data visible

        // ===== COMPUTE: G1(tau) on waves 0-3 || G2(tau-1)+head(tau-2) on 4-7 =====
        if (eng == 0){
            if (tau < Tn){
                v4f acc0 = {0.f,0.f,0.f,0.f}, acc1 = {0.f,0.f,0.f,0.f};
                {   // k-tile 0: x part (double-buffered, 16 cols incl zero pad)
                    v4h a = *(const v4h*)(XBp + (tau & 1)*512 + (m*16 + ln15)*16 + ln4*4);
                    acc0 = __builtin_amdgcn_mfma_f32_16x16x16f16(a, W[0], acc0, 0,0,0);
                    acc1 = __builtin_amdgcn_mfma_f32_16x16x16f16(a, W[1], acc1, 0,0,0);
                }
                const _Float16* Ap = H1l + (m*16 + ln15)*H1S + ln4*4;
                #pragma unroll
                for (int k = 0; k < 16; ++k){
                    v4h a = *(const v4h*)(Ap + k*16);
                    acc0 = __builtin_amdgcn_mfma_f32_16x16x16f16(a, W[2+k],  acc0, 0,0,0);
                    acc1 = __builtin_amdgcn_mfma_f32_16x16x16f16(a, W[18+k], acc1, 0,0,0);
                }
                _Float16* d0 = h1g + (size_t)(tau & 3)*(Bn*Hn)
                             + (size_t)(r0 + m*16 + ln15)*Hn + u0 + n0*4;
                lstm_ew_publish(acc0, gw, b1s, n0,   ca, d0,     ln15, ln4);
                lstm_ew_publish(acc1, gw, b1s, n0+1, cb, d0 + 4, ln15, ln4);
                asm volatile("s_waitcnt vmcnt(0)" ::: "memory");
                if (lane == 0)
                    __hip_atomic_store(&tags1[rt*64 + us*4 + wq], tau + 1,
                                       __ATOMIC_RELAXED, __HIP_MEMORY_SCOPE_AGENT);
            }
        } else {
            if (wv == 6 && lane < 32 && tau + 1 < Tn){
                _Float16* xd = XBp + ((tau+1) & 1)*512 + lane*16;
                #pragma unroll
                for (int i = 0; i < 10; ++i) xd[i] = (_Float16)xr[i];
            }
            if (tau >= 1 && tau <= Tn){
                v4f acc0 = {0.f,0.f,0.f,0.f}, acc1 = {0.f,0.f,0.f,0.f};
                const _Float16* Ap1 = H1l + (m*16 + ln15)*H1S + ln4*4;
                const _Float16* Ap2 = H2l + (m*16 + ln15)*H2S + ln4*4;
                #pragma unroll
                for (int k = 0; k < 16; ++k){
                    v4h a = *(const v4h*)(Ap1 + k*16);
                    acc0 = __builtin_amdgcn_mfma_f32_16x16x16f16(a, W[k],    acc0, 0,0,0);
                    acc1 = __builtin_amdgcn_mfma_f32_16x16x16f16(a, W[16+k], acc1, 0,0,0);
                }
                #pragma unroll
                for (int k = 0; k < 16; ++k){
                    v4h a = *(const v4h*)(Ap2 + k*16);
                    acc0 = __builtin_amdgcn_mfma_f32_16x16x16f16(a, W[32+k], acc0, 0,0,0);
                    acc1 = __builtin_amdgcn_mfma_f32_16x16x16f16(a, W[48+k], acc1, 0,0,0);
                }
                _Float16* d0 = h2g + (size_t)((tau + 3) & 3)*(Bn*Hn)
                             + (size_t)(r0 + m*16 + ln15)*Hn + u0 + n0*4;
                lstm_ew_publish(acc0, gw, b2s, n0,   ca, d0,     ln15, ln4);
                lstm_ew_publish(acc1, gw, b2s, n0+1, cb, d0 + 4, ln15, ln4);
                asm volatile("s_waitcnt vmcnt(0)" ::: "memory");
                if (lane == 0)
                    __hip_atomic_store(&tags2[rt*64 + us*4 + wq], tau,
                                       __ATOMIC_RELAXED, __HIP_MEMORY_SCOPE_AGENT);
            }
            if ((wv == 4 || wv == 5) && tau >= 2){
                const int mh = wv & 1;
                v4f acc = {0.f,0.f,0.f,0.f};
                const _Float16* Ap = H2l + (mh*16 + ln15)*H2S + ln4*4;
                const _Float16* Bp = WHl + ln15*WHS + ln4*4;
                #pragma unroll
                for (int k = 0; k < 16; ++k)
                    acc = __builtin_amdgcn_mfma_f32_16x16x16f16(*(const v4h*)(Ap + k*16),
                                                                *(const v4h*)(Bp + k*16), acc, 0, 0, 0);
                float bh = bhs[ln15], w2 = w2hs[ln15];
                float t0 = fmaxf(acc[0] + bh, 0.f) * w2;
                float t1 = fmaxf(acc[1] + bh, 0.f) * w2;
                float t2 = fmaxf(acc[2] + bh, 0.f) * w2;
                float t3 = fmaxf(acc[3] + bh, 0.f) * w2;
                #pragma unroll
                for (int mk = 1; mk <= 8; mk <<= 1){
                    t0 += __shfl_xor(t0, mk, 64);
                    t1 += __shfl_xor(t1, mk, 64);
                    t2 += __shfl_xor(t2, mk, 64);
                    t3 += __shfl_xor(t3, mk, 64);
                }
                if (ln15 == 0){
                    float* sp = scores + (size_t)(tau - 2)*Bn + r0 + mh*16 + ln4*4;
                    atomicAdd(sp + 0, t0);
                    atomicAdd(sp + 1, t1);
                    atomicAdd(sp + 2, t2);
                    atomicAdd(sp + 3, t3);
                }
            }
        }
        __syncthreads();   // B: compute done; stage(tau+1) may overwrite H1l/H2l
    }
}

// mixed[b] = scores.flat[b*1024 .. b*1024+1023]  (time-major flatten == contiguous)
__global__ __launch_bounds__(256)
void softmax_adv(const float* __restrict__ scores, float* __restrict__ out)
{
    const int b = blockIdx.x, tid = threadIdx.x;
    const int lane = tid & 63, wv = tid >> 6;
    __shared__ float red[4];
    const float4* sp = (const float4*)(scores + (size_t)b*1024);
    float4 v = sp[tid];
    float m = fmaxf(fmaxf(v.x, v.y), fmaxf(v.z, v.w));
    #pragma unroll
    for (int o = 32; o > 0; o >>= 1) m = fmaxf(m, __shfl_xor(m, o, 64));
    if (lane == 0) red[wv] = m;
    __syncthreads();
    m = fmaxf(fmaxf(red[0], red[1]), fmaxf(red[2], red[3]));
    __syncthreads();
    float e0 = __expf(v.x - m), e1 = __expf(v.y - m);
    float e2 = __expf(v.z - m), e3 = __expf(v.w - m);
    float s = e0 + e1 + e2 + e3;
    #pragma unroll
    for (int o = 32; o > 0; o >>= 1) s += __shfl_xor(s, o, 64);
    if (lane == 0) red[wv] = s;
    __syncthreads();
    s = red[0] + red[1] + red[2] + red[3];
    float inv = 1.0f / s;
    float4 o4; o4.x = e0*inv; o4.y = e1*inv; o4.z = e2*inv; o4.w = e3*inv;
    ((float4*)(out + (size_t)b*1024))[tid] = o4;
}

extern "C" void kernel_launch(void* const* d_in, const int* in_sizes, int n_in,
                              void* d_out, int out_size, void* d_ws, size_t ws_size,
                              hipStream_t stream)
{
    (void)in_sizes; (void)n_in; (void)out_size; (void)ws_size;
    const float* x      = (const float*)d_in[0];
    const float* w_ih0  = (const float*)d_in[1];
    const float* w_hh0  = (const float*)d_in[2];
    const float* b_ih0  = (const float*)d_in[3];
    const float* b_hh0  = (const float*)d_in[4];
    const float* w_ih1  = (const float*)d_in[5];
    const float* w_hh1  = (const float*)d_in[6];
    const float* b_ih1  = (const float*)d_in[7];
    const float* b_hh1  = (const float*)d_in[8];
    const float* adv_w1 = (const float*)d_in[9];
    const float* adv_b1 = (const float*)d_in[10];
    const float* adv_w2 = (const float*)d_in[11];
    // adv_w2 bias (d_in[12]) cancels in softmax — unused.

    float*    scores = (float*)((char*)d_ws + SCORES_OFF);
    _Float16* h1g    = (_Float16*)((char*)d_ws + H1G_OFF);
    _Float16* h2g    = (_Float16*)((char*)d_ws + H2G_OFF);
    int*      flags  = (int*)((char*)d_ws + FLAG_OFF);

    hipMemsetAsync(d_ws, 0, WS_USED, stream);
    hipFuncSetAttribute((const void*)lstm_pipe,
                        hipFuncAttributeMaxDynamicSharedMemorySize, LDS_TOTAL);

    hipLaunchKernelGGL(lstm_pipe, dim3(256), dim3(512), LDS_TOTAL, stream,
                       x, w_ih0, w_hh0, b_ih0, b_hh0, w_ih1, w_hh1, b_ih1, b_hh1,
                       adv_w1, adv_b1, adv_w2, scores, h1g, h2g, flags);
    hipLaunchKernelGGL(softmax_adv, dim3(512), dim3(256), 0, stream,
                       scores, (float*)d_out);
}

// Round 8
// 3924.225 us; speedup vs baseline: 1.7337x; 1.1129x over previous
//
#include <hip/hip_runtime.h>
#include <cstdint>
#include <cstddef>

// Problem constants
#define Tn 1024
#define Bn 512
#define Hn 256

// Partition: 512 blocks = 32 row-tiles (16 rows) x 16 unit-slices (16 units).
// 256 threads/block, 4 waves: waves 0-1 = layer-1 engine, waves 2-3 = layer-2+head.
// 78KB LDS -> exactly 2 blocks/CU co-resident: while one block waits on the
// exchange (poll/stage vmcnt), the other computes -> TLP latency hiding.
// Work, exchange volume, and protocol semantics identical to the R7 kernel.
#define H1S 264
#define H2S 264
#define WHS 264
#define GWS 20    // per-wave gate scratch row stride (floats)

#define H1_OFF  0
#define H2_OFF  (H1_OFF + 16*H1S*2)      // 8448
#define XB_OFF  (H2_OFF + 16*H2S*2)      // 16896
#define WH_OFF  (XB_OFF + 2*16*16*2)     // 17920
#define GW_OFF  (WH_OFF + 16*WHS*2)      // 26368
#define B1_OFF  (GW_OFF + 4*16*GWS*4)    // 31488
#define B2_OFF  (B1_OFF + 64*4)
#define BH_OFF  (B2_OFF + 64*4)
#define W2H_OFF (BH_OFF + 16*4)
#define DEAD_OFF (W2H_OFF + 16*4)        // 32128
// 78KB: 2 blocks/CU fit (156KB <= 160KB), 3 do not.
#define LDS_TOTAL 79872

// ws layout (bytes)
#define SCORES_OFF 0                      // [1024][512] f32 = 2MB
#define H1G_OFF  (2*1024*1024)            // 4 slots x [512][256] fp16 = 1MB
#define H2G_OFF  (3*1024*1024)            // 1MB
#define FLAG_OFF (4*1024*1024)            // tags1[1024], tags2 at +1024 ints
#define WS_USED  (4*1024*1024 + 8192)

#define POLL_GUARD (1 << 22)

typedef _Float16 v4h __attribute__((ext_vector_type(4)));
typedef float    v4f __attribute__((ext_vector_type(4)));
typedef unsigned int u32x4 __attribute__((ext_vector_type(4)));
typedef unsigned long long u64;

__device__ inline float sigm(float x){ return 1.0f/(1.0f + __expf(-x)); }
__device__ inline float tanh_f(float x){ return 1.0f - 2.0f/(1.0f + __expf(2.0f*x)); }

__device__ inline v4h cvt4(float4 a){
    v4h f; f[0]=(_Float16)a.x; f[1]=(_Float16)a.y; f[2]=(_Float16)a.z; f[3]=(_Float16)a.w;
    return f;
}

// 32 per-producer-wave tags per row-tile group: lane (l&31) watches one tag.
// Returns false when the watchdog trips (residency/protocol broken).
__device__ inline bool poll32(const int* tags, int tgt){
    int idx = threadIdx.x & 31;
    int guard = 0;
    while (true){
        int t = __hip_atomic_load(&tags[idx], __ATOMIC_RELAXED, __HIP_MEMORY_SCOPE_AGENT);
        if (__ballot(t < tgt) == 0ull) return true;
        if (++guard > POLL_GUARD) return false;
        __builtin_amdgcn_s_sleep(1);
    }
}

// Coalesced 8KB tile stage (16 rows x 512B): thread t (0..127) loads 4x16B at
// o = j*2048 + t*16 (per-instruction lane-contiguous), sc0+sc1 = device-coherent.
// Safe vs tearing: all producer tags polled before any read; producers drain
// vmcnt(0) before tagging. LDS write applies the 528B padded row stride.
#define LADDR(oo) ( (size_t)(((oo)>>9)*528 + ((oo)&511)) )
__device__ __forceinline__ void stage_tile8(const char* gbase, char* lbase, int t){
    u32x4 q0,q1,q2,q3;
    const char* p0 = gbase + t*16;
    const char* p1 = p0 + 2048;
    const char* p2 = p0 + 4096;
    const char* p3 = p0 + 6144;
    asm volatile("global_load_dwordx4 %0, %1, off sc0 sc1" : "=v"(q0) : "v"(p0));
    asm volatile("global_load_dwordx4 %0, %1, off sc0 sc1" : "=v"(q1) : "v"(p1));
    asm volatile("global_load_dwordx4 %0, %1, off sc0 sc1" : "=v"(q2) : "v"(p2));
    asm volatile("global_load_dwordx4 %0, %1, off sc0 sc1" : "=v"(q3) : "v"(p3));
    asm volatile("s_waitcnt vmcnt(0)"
                 : "+v"(q0), "+v"(q1), "+v"(q2), "+v"(q3) :: "memory");
    const int o = t*16;
    *(u32x4*)(lbase + LADDR(o))        = q0;
    *(u32x4*)(lbase + LADDR(o + 2048)) = q1;
    *(u32x4*)(lbase + LADDR(o + 4096)) = q2;
    *(u32x4*)(lbase + LADDR(o + 6144)) = q3;
}

// LSTM elementwise + publish for one 16x16 gate tile (tile-local col = 4*unit+gate).
__device__ __forceinline__ void lstm_ew_publish(v4f acc, float* gw, const float* bs,
                                                int n, float& c, _Float16* dst,
                                                int ln15, int ln4)
{
    #pragma unroll
    for (int r = 0; r < 4; ++r) gw[(ln4*4 + r)*GWS + ln15] = acc[r];
    asm volatile("s_waitcnt lgkmcnt(0)" ::: "memory");
    v4f g4 = *(const v4f*)(gw + ln15*GWS + ln4*4);
    asm volatile("s_waitcnt lgkmcnt(0)" ::: "memory");
    v4f bb = *(const v4f*)(bs + n*16 + ln4*4);
    float gi = sigm(g4.x + bb.x), gf = sigm(g4.y + bb.y);
    float gg = tanh_f(g4.z + bb.z), go = sigm(g4.w + bb.w);
    c = gf*c + gi*gg;
    float hn = go * tanh_f(c);
    union { _Float16 h; unsigned short u; } cvt; cvt.h = (_Float16)hn;
    unsigned v32 = cvt.u;
    unsigned p16 = (unsigned)__shfl_xor((int)v32, 16, 64);
    unsigned lo32 = v32 | (p16 << 16);
    unsigned hi32 = (unsigned)__shfl_xor((int)lo32, 32, 64);
    if (ln4 == 0){
        u64 pk = (u64)lo32 | ((u64)hi32 << 32);
        __hip_atomic_store((u64*)dst, pk, __ATOMIC_RELAXED, __HIP_MEMORY_SCOPE_AGENT);
    }
}

__global__ __launch_bounds__(256)
void lstm_pipe(const float* __restrict__ x,
               const float* __restrict__ w_ih0, const float* __restrict__ w_hh0,
               const float* __restrict__ b_ih0, const float* __restrict__ b_hh0,
               const float* __restrict__ w_ih1, const float* __restrict__ w_hh1,
               const float* __restrict__ b_ih1, const float* __restrict__ b_hh1,
               const float* __restrict__ adv_w1, const float* __restrict__ adv_b1,
               const float* __restrict__ adv_w2,
               float* __restrict__ scores, _Float16* __restrict__ h1g,
               _Float16* __restrict__ h2g, int* __restrict__ flags)
{
    extern __shared__ char smem[];
    _Float16* H1l = (_Float16*)(smem + H1_OFF);
    _Float16* H2l = (_Float16*)(smem + H2_OFF);
    _Float16* XBp = (_Float16*)(smem + XB_OFF);
    _Float16* WHl = (_Float16*)(smem + WH_OFF);
    float* gatesc = (float*)(smem + GW_OFF);
    float* b1s    = (float*)(smem + B1_OFF);
    float* b2s    = (float*)(smem + B2_OFF);
    float* bhs    = (float*)(smem + BH_OFF);
    float* w2hs   = (float*)(smem + W2H_OFF);
    volatile int* deadp = (volatile int*)(smem + DEAD_OFF);

    const int tid  = threadIdx.x;
    const int lane = tid & 63;
    const int wv   = tid >> 6;             // 0..3
    const int ln15 = lane & 15;
    const int ln4  = lane >> 4;
    const int rt = blockIdx.x >> 4;        // 0..31 (16-row tile)
    const int us = blockIdx.x & 15;        // 0..15 (16-unit slice)
    const int r0 = rt * 16;
    const int u0 = us * 16;
    const int eng = wv >> 1;               // 0 = L1 engine, 1 = L2+head engine
    const int wq  = wv & 1;                // engine-wave id
    const int n0  = wq * 2;                // first of two 16-col gate tiles

    int* tags1 = flags;            // [32 rt][16 us][2 wq]
    int* tags2 = flags + 1024;

    if (tid == 0) *deadp = 0;

    // ---- one-time weight fragments -> VGPRs (gate-interleaved row N=4*u+g) ----
    const int N0i = n0*16 + ln15;
    const int R0 = (N0i & 3)*256 + u0 + (N0i >> 2);
    const int N1i = N0i + 16;
    const int R1 = (N1i & 3)*256 + u0 + (N1i >> 2);
    v4h W[64];
    if (eng == 0){
        #pragma unroll
        for (int t = 0; t < 2; ++t){
            const int R = t ? R1 : R0;
            v4h f;
            #pragma unroll
            for (int j = 0; j < 4; ++j){
                int c = ln4*4 + j;
                f[j] = (_Float16)((c < 10) ? w_ih0[R*10 + c] : 0.f);
            }
            W[t] = f;
        }
        #pragma unroll
        for (int k = 0; k < 16; ++k){
            float4 a0 = *(const float4*)(w_hh0 + (size_t)R0*256 + k*16 + ln4*4);
            float4 a1 = *(const float4*)(w_hh0 + (size_t)R1*256 + k*16 + ln4*4);
            W[2+k]  = cvt4(a0);
            W[18+k] = cvt4(a1);
        }
    } else {
        #pragma unroll
        for (int k = 0; k < 16; ++k){
            float4 a0 = *(const float4*)(w_ih1 + (size_t)R0*256 + k*16 + ln4*4);
            float4 a1 = *(const float4*)(w_ih1 + (size_t)R1*256 + k*16 + ln4*4);
            float4 b0 = *(const float4*)(w_hh1 + (size_t)R0*256 + k*16 + ln4*4);
            float4 b1 = *(const float4*)(w_hh1 + (size_t)R1*256 + k*16 + ln4*4);
            W[k]    = cvt4(a0);
            W[16+k] = cvt4(a1);
            W[32+k] = cvt4(b0);
            W[48+k] = cvt4(b1);
        }
    }

    // ---- LDS one-time: head weights, biases, x buffer ----
    for (int idx = tid; idx < 16*WHS; idx += 256){
        int n = idx / WHS, c = idx - n*WHS;
        float v = (c < 256) ? adv_w1[(u0+n)*256 + c] : 0.f;
        WHl[idx] = (_Float16)v;
    }
    if (tid < 64){
        int R = (tid & 3)*256 + u0 + (tid >> 2);
        b1s[tid] = b_ih0[R] + b_hh0[R];
        b2s[tid] = b_ih1[R] + b_hh1[R];
    }
    if (tid < 16){
        bhs[tid]  = adv_b1[u0 + tid];
        w2hs[tid] = adv_w2[u0 + tid];
    }
    // zero x double-buffer, then stage x(0)
    for (int idx = tid; idx < 512; idx += 256) XBp[idx] = (_Float16)0.f;
    __syncthreads();
    if (tid < 16){
        const float* xp = x + ((size_t)(r0 + tid)*Tn + 0)*10;
        #pragma unroll
        for (int i = 0; i < 10; ++i) XBp[tid*16 + i] = (_Float16)xp[i];
    }
    __syncthreads();

    // cell states: each wave holds c for its two gate tiles.
    float ca = 0.f, cb = 0.f;
    float* gw = gatesc + wv*(16*GWS);      // wave-private gate scratch

    for (int tau = 0; tau <= Tn + 1; ++tau){
        float xr[10];
        // ===== x prefetch issue (independent of polls) =====
        if (wv == 3 && lane < 16 && tau + 1 < Tn){
            const float* xp = x + ((size_t)(r0 + lane)*Tn + (tau+1))*10;
            #pragma unroll
            for (int i = 0; i < 10; ++i) xr[i] = xp[i];
        }
        // ===== POLL: one wave per engine, watchdog-bounded =====
        if (wv == 0 && tau >= 1 && tau <= Tn){
            if (!poll32(tags1 + rt*32, tau) && lane == 0) *deadp = 1;
        }
        if (wv == 2 && tau >= 2){
            if (!poll32(tags2 + rt*32, tau - 1) && lane == 0) *deadp = 1;
        }
        asm volatile("" ::: "memory");
        __syncthreads();   // A0: tags satisfied for both engines
        if (*deadp) return;   // bounded failure instead of hang

        // ===== STAGE: coalesced 16B sc0+sc1 loads -> LDS =====
        if (eng == 0){
            if (tau <= Tn){
                const int slot = (tau + 3) & 3;          // (tau-1)&3
                stage_tile8((const char*)(h1g + (size_t)slot*(Bn*Hn) + (size_t)r0*Hn),
                            (char*)H1l, tid);            // t in [0,128)
            }
        } else {
            if (tau >= 1){
                const int slot = (tau + 2) & 3;          // (tau-2)&3
                stage_tile8((const char*)(h2g + (size_t)slot*(Bn*Hn) + (size_t)r0*Hn),
                            (char*)H2l, tid - 128);
            }
        }
        __syncthreads();   // A: staged data visible

        // ===== COMPUTE: G1(tau) on waves 0-1 || G2(tau-1)+head(tau-2) on 2-3 =====
        if (eng == 0){
            if (tau < Tn){
                v4f acc0 = {0.f,0.f,0.f,0.f}, acc1 = {0.f,0.f,0.f,0.f};
                {   // k-tile 0: x part (double-buffered, 16 cols incl zero pad)
                    v4h a = *(const v4h*)(XBp + (tau & 1)*256 + ln15*16 + ln4*4);
                    acc0 = __builtin_amdgcn_mfma_f32_16x16x16f16(a, W[0], acc0, 0,0,0);
                    acc1 = __builtin_amdgcn_mfma_f32_16x16x16f16(a, W[1], acc1, 0,0,0);
                }
                const _Float16* Ap = H1l + ln15*H1S + ln4*4;
                #pragma unroll
                for (int k = 0; k < 16; ++k){
                    v4h a = *(const v4h*)(Ap + k*16);
                    acc0 = __builtin_amdgcn_mfma_f32_16x16x16f16(a, W[2+k],  acc0, 0,0,0);
                    acc1 = __builtin_amdgcn_mfma_f32_16x16x16f16(a, W[18+k], acc1, 0,0,0);
                }
                _Float16* d0 = h1g + (size_t)(tau & 3)*(Bn*Hn)
                             + (size_t)(r0 + ln15)*Hn + u0 + n0*4;
                lstm_ew_publish(acc0, gw, b1s, n0,   ca, d0,     ln15, ln4);
                lstm_ew_publish(acc1, gw, b1s, n0+1, cb, d0 + 4, ln15, ln4);
                asm volatile("s_waitcnt vmcnt(0)" ::: "memory");
                if (lane == 0)
                    __hip_atomic_store(&tags1[rt*32 + us*2 + wq], tau + 1,
                                       __ATOMIC_RELAXED, __HIP_MEMORY_SCOPE_AGENT);
            }
        } else {
            if (wv == 3 && lane < 16 && tau + 1 < Tn){
                _Float16* xd = XBp + ((tau+1) & 1)*256 + lane*16;
                #pragma unroll
                for (int i = 0; i < 10; ++i) xd[i] = (_Float16)xr[i];
            }
            if (tau >= 1 && tau <= Tn){
                v4f acc0 = {0.f,0.f,0.f,0.f}, acc1 = {0.f,0.f,0.f,0.f};
                const _Float16* Ap1 = H1l + ln15*H1S + ln4*4;
                const _Float16* Ap2 = H2l + ln15*H2S + ln4*4;
                #pragma unroll
                for (int k = 0; k < 16; ++k){
                    v4h a = *(const v4h*)(Ap1 + k*16);
                    acc0 = __builtin_amdgcn_mfma_f32_16x16x16f16(a, W[k],    acc0, 0,0,0);
                    acc1 = __builtin_amdgcn_mfma_f32_16x16x16f16(a, W[16+k], acc1, 0,0,0);
                }
                #pragma unroll
                for (int k = 0; k < 16; ++k){
                    v4h a = *(const v4h*)(Ap2 + k*16);
                    acc0 = __builtin_amdgcn_mfma_f32_16x16x16f16(a, W[32+k], acc0, 0,0,0);
                    acc1 = __builtin_amdgcn_mfma_f32_16x16x16f16(a, W[48+k], acc1, 0,0,0);
                }
                _Float16* d0 = h2g + (size_t)((tau + 3) & 3)*(Bn*Hn)
                             + (size_t)(r0 + ln15)*Hn + u0 + n0*4;
                lstm_ew_publish(acc0, gw, b2s, n0,   ca, d0,     ln15, ln4);
                lstm_ew_publish(acc1, gw, b2s, n0+1, cb, d0 + 4, ln15, ln4);
                asm volatile("s_waitcnt vmcnt(0)" ::: "memory");
                if (lane == 0)
                    __hip_atomic_store(&tags2[rt*32 + us*2 + wq], tau,
                                       __ATOMIC_RELAXED, __HIP_MEMORY_SCOPE_AGENT);
            }
            if (wv == 2 && tau >= 2){
                v4f acc = {0.f,0.f,0.f,0.f};
                const _Float16* Ap = H2l + ln15*H2S + ln4*4;
                const _Float16* Bp = WHl + ln15*WHS + ln4*4;
                #pragma unroll
                for (int k = 0; k < 16; ++k)
                    acc = __builtin_amdgcn_mfma_f32_16x16x16f16(*(const v4h*)(Ap + k*16),
                                                                *(const v4h*)(Bp + k*16), acc, 0, 0, 0);
                float bh = bhs[ln15], w2 = w2hs[ln15];
                float t0 = fmaxf(acc[0] + bh, 0.f) * w2;
                float t1 = fmaxf(acc[1] + bh, 0.f) * w2;
                float t2 = fmaxf(acc[2] + bh, 0.f) * w2;
                float t3 = fmaxf(acc[3] + bh, 0.f) * w2;
                #pragma unroll
                for (int mk = 1; mk <= 8; mk <<= 1){
                    t0 += __shfl_xor(t0, mk, 64);
                    t1 += __shfl_xor(t1, mk, 64);
                    t2 += __shfl_xor(t2, mk, 64);
                    t3 += __shfl_xor(t3, mk, 64);
                }
                if (ln15 == 0){
                    float* sp = scores + (size_t)(tau - 2)*Bn + r0 + ln4*4;
                    atomicAdd(sp + 0, t0);
                    atomicAdd(sp + 1, t1);
                    atomicAdd(sp + 2, t2);
                    atomicAdd(sp + 3, t3);
                }
            }
        }
        __syncthreads();   // B: compute done; stage(tau+1) may overwrite H1l/H2l
    }
}

// mixed[b] = scores.flat[b*1024 .. b*1024+1023]  (time-major flatten == contiguous)
__global__ __launch_bounds__(256)
void softmax_adv(const float* __restrict__ scores, float* __restrict__ out)
{
    const int b = blockIdx.x, tid = threadIdx.x;
    const int lane = tid & 63, wv = tid >> 6;
    __shared__ float red[4];
    const float4* sp = (const float4*)(scores + (size_t)b*1024);
    float4 v = sp[tid];
    float m = fmaxf(fmaxf(v.x, v.y), fmaxf(v.z, v.w));
    #pragma unroll
    for (int o = 32; o > 0; o >>= 1) m = fmaxf(m, __shfl_xor(m, o, 64));
    if (lane == 0) red[wv] = m;
    __syncthreads();
    m = fmaxf(fmaxf(red[0], red[1]), fmaxf(red[2], red[3]));
    __syncthreads();
    float e0 = __expf(v.x - m), e1 = __expf(v.y - m);
    float e2 = __expf(v.z - m), e3 = __expf(v.w - m);
    float s = e0 + e1 + e2 + e3;
    #pragma unroll
    for (int o = 32; o > 0; o >>= 1) s += __shfl_xor(s, o, 64);
    if (lane == 0) red[wv] = s;
    __syncthreads();
    s = red[0] + red[1] + red[2] + red[3];
    float inv = 1.0f / s;
    float4 o4; o4.x = e0*inv; o4.y = e1*inv; o4.z = e2*inv; o4.w = e3*inv;
    ((float4*)(out + (size_t)b*1024))[tid] = o4;
}

extern "C" void kernel_launch(void* const* d_in, const int* in_sizes, int n_in,
                              void* d_out, int out_size, void* d_ws, size_t ws_size,
                              hipStream_t stream)
{
    (void)in_sizes; (void)n_in; (void)out_size; (void)ws_size;
    const float* x      = (const float*)d_in[0];
    const float* w_ih0  = (const float*)d_in[1];
    const float* w_hh0  = (const float*)d_in[2];
    const float* b_ih0  = (const float*)d_in[3];
    const float* b_hh0  = (const float*)d_in[4];
    const float* w_ih1  = (const float*)d_in[5];
    const float* w_hh1  = (const float*)d_in[6];
    const float* b_ih1  = (const float*)d_in[7];
    const float* b_hh1  = (const float*)d_in[8];
    const float* adv_w1 = (const float*)d_in[9];
    const float* adv_b1 = (const float*)d_in[10];
    const float* adv_w2 = (const float*)d_in[11];
    // adv_w2 bias (d_in[12]) cancels in softmax — unused.

    float*    scores = (float*)((char*)d_ws + SCORES_OFF);
    _Float16* h1g    = (_Float16*)((char*)d_ws + H1G_OFF);
    _Float16* h2g    = (_Float16*)((char*)d_ws + H2G_OFF);
    int*      flags  = (int*)((char*)d_ws + FLAG_OFF);

    hipMemsetAsync(d_ws, 0, WS_USED, stream);
    hipFuncSetAttribute((const void*)lstm_pipe,
                        hipFuncAttributeMaxDynamicSharedMemorySize, LDS_TOTAL);

    hipLaunchKernelGGL(lstm_pipe, dim3(512), dim3(256), LDS_TOTAL, stream,
                       x, w_ih0, w_hh0, b_ih0, b_hh0, w_ih1, w_hh1, b_ih1, b_hh1,
                       adv_w1, adv_b1, adv_w2, scores, h1g, h2g, flags);
    hipLaunchKernelGGL(softmax_adv, dim3(512), dim3(256), 0, stream,
                       scores, (float*)d_out);
}